// Round 13
// baseline (275.111 us; speedup 1.0000x reference)
//
#include <hip/hip_runtime.h>

// TDT loss, fixed shapes from setup_inputs():
#define TDT_B  8
#define TDT_T  256
#define TDT_U  64
#define TDT_U1 65
#define TDT_V1 513   // V+1, blank index = 512
#define TP     275   // 4 zero-pad slices + 256 + slack
#define SIG    0.05f
#define SHIFT  3.0f  // exponent shift PER TIME-STEP: duration-d weight carries SHIFT*d
#define REPS   12    // instrumentation: DP repeated; only last rep writes out

// ws layout (floats):
//   WB: float4[B][TP][U1] = exp(lpb + ld_i - SIG + SHIFT*(i+1))
//   WY: float4[B][TP][U]  = exp(lpy + ld_i - SIG + SHIFT*(i+1))
//   GC: float4[B][TP]     = WB[b][tp][u=64]  (compact G column)
#define OFF_PYD 572000                        // 8*275*65*4
#define OFF_GC  1135200                       // + 8*275*64*4; GC = 8800 floats

// Kernel 1: per-(b,t,u) row log-softmax over 513 labels (wave per row, float2
// loads with odd-row alignment shim), duration log-softmax over 4, write
// EXP-DOMAIN W records with per-duration scale e^{SHIFT*d}. Zero pads tau<0.
__global__ __launch_bounds__(256) void k_prep(
    const float* __restrict__ la, const float* __restrict__ da,
    const int* __restrict__ tgt, float* __restrict__ ws,
    float* __restrict__ out)
{
  if (blockIdx.x == 0 && threadIdx.x == 0) out[0] = 0.f;

  const int l = threadIdx.x & 63;
  const int r = (blockIdx.x << 2) + (threadIdx.x >> 6);   // row in [0, B*T*U1)
  const int u  = r % TDT_U1;
  const int bt = r / TDT_U1;
  const int t  = bt & (TDT_T - 1);
  const int b  = bt >> 8;

  const float* row = la + (size_t)r * TDT_V1;
  const int ofs = r & 1;                    // odd rows: shift by 1 for 8B align
  const float2* p2 = (const float2*)(row + ofs);
  float2 w[4];
#pragma unroll
  for (int k = 0; k < 4; ++k) w[k] = p2[l + (k << 6)];  // elems ofs+2l+128k+{0,1}
  const float extra = row[ofs ? 0 : 512];   // the one element outside the vec span

  float m = extra;
#pragma unroll
  for (int k = 0; k < 4; ++k) m = fmaxf(m, fmaxf(w[k].x, w[k].y));
#pragma unroll
  for (int off = 32; off; off >>= 1) m = fmaxf(m, __shfl_xor(m, off));
  float s = (l == 0) ? __expf(extra - m) : 0.f;
#pragma unroll
  for (int k = 0; k < 4; ++k) s += __expf(w[k].x - m) + __expf(w[k].y - m);
#pragma unroll
  for (int off = 32; off; off >>= 1) s += __shfl_xor(s, off);
  const float lse = m + __logf(s);

  // duration log-softmax (uniform per wave)
  const float4 dv = *(const float4*)(da + ((size_t)r << 2));
  const float m4 = fmaxf(fmaxf(dv.x, dv.y), fmaxf(dv.z, dv.w));
  const float l4 = m4 + __logf(__expf(dv.x - m4) + __expf(dv.y - m4) +
                               __expf(dv.z - m4) + __expf(dv.w - m4));
  // per-duration: ld_i - l4 + SHIFT*(i+1)  (scale-consistent exp domain)
  const float d0 = dv.x - l4 + SHIFT * 1.0f;
  const float d1 = dv.y - l4 + SHIFT * 2.0f;
  const float d2 = dv.z - l4 + SHIFT * 3.0f;
  const float d3 = dv.w - l4 + SHIFT * 4.0f;

  float4* WB4 = (float4*)ws;
  float4* WY4 = (float4*)(ws + OFF_PYD);
  float4* GC4 = (float4*)(ws + OFF_GC);

  const int tp = t + 4;
  // blank logit = elem 512: ofs==0 -> extra (owner lane 0); ofs==1 -> w[3].y (lane 63)
  const float xb = ofs ? w[3].y : extra;
  if (l == (ofs ? 63 : 0)) {
    const float pb = xb - lse - SIG;
    const float4 wb = make_float4(__expf(pb + d0), __expf(pb + d1),
                                  __expf(pb + d2), __expf(pb + d3));
    WB4[(b * TP + tp) * TDT_U1 + u] = wb;
    if (u == TDT_U) GC4[b * TP + tp] = wb;
  }

  // target gather (exactly one lane owns it); static indices only
  const int tg = (u < TDT_U) ? tgt[b * TDT_U + u] : -1;   // tg in [0,512)
  bool own = false; float vt = 0.f;
#pragma unroll
  for (int k = 0; k < 4; ++k) {
    const int base = ofs + ((l + (k << 6)) << 1);
    if (base == tg)     { vt = w[k].x; own = true; }
    if (base + 1 == tg) { vt = w[k].y; own = true; }
  }
  if (ofs && tg == 0 && l == 0) { vt = extra; own = true; }
  if (own) {
    const float py = vt - lse - SIG;
    WY4[(b * TP + tp) * TDT_U + u] =
        make_float4(__expf(py + d0), __expf(py + d1), __expf(py + d2), __expf(py + d3));
  }

  // zero pads for tau < 0 (slices tp = 0..3): exp(-inf) = 0
  if (t < 4 && l == 0) {
    const float4 z4 = make_float4(0.f, 0.f, 0.f, 0.f);
    WB4[(b * TP + t) * TDT_U1 + u] = z4;
    if (u == TDT_U) GC4[b * TP + t] = z4;
    if (u < TDT_U)  WY4[(b * TP + t) * TDT_U + u] = z4;
  }
}

// DPP wave_shr:1 (ctrl 0x138), bound_ctrl=1 -> lane 0 reads 0. VALU-pipe
// lane shift replacing ds_bpermute on the serial t-chain.
__device__ __forceinline__ float shup1(float x) {
  const int r = __builtin_amdgcn_update_dpp(
      0, __float_as_int(x), 0x138, 0xf, 0xf, true);
  return __int_as_float(r);
}

// Direct HBM->LDS DMA, 16B/lane: lane l's data lands at ldsbase + l*16.
__device__ __forceinline__ void gl2lds16(const float4* g, float4* lds) {
  __builtin_amdgcn_global_load_lds(
      (const __attribute__((address_space(1))) void*)g,
      (__attribute__((address_space(3))) void*)lds, 16, 0, 0);
}

// Loader helper: fill group j (slices 15j+1 .. 15j+15) into ring third j%3.
// Slice s -> ring slot (s-1)%45; slot holds B[u=0..63] then Y[u=0..63].
__device__ __forceinline__ void fill_group(
    const float4* __restrict__ WB4p, const float4* __restrict__ WY4p,
    float4* ring, int j, int wv, int l)
{
  const int sb = 15 * j + wv;               // this wave's first slice in group
  const int rb = 15 * (j % 3) + (wv - 1);   // its first ring slot
#pragma unroll
  for (int k = 0; k < 5; ++k) {
    const int s    = sb + 3 * k;
    const int slot = rb + 3 * k;
    gl2lds16(WB4p + (size_t)s * TDT_U1 + l, ring + slot * 128);
    gl2lds16(WY4p + (size_t)s * TDT_U  + l, ring + slot * 128 + 64);
  }
}

// Kernel 2: forward DP, exp domain. 8 blocks (one per b) x 4 waves.
// Wave 0: serial chain; depth-5 NAMED register FIFO fed by ds_read from the
// 45-slice LDS ring. Waves 1-3: global_load_lds-stream W slices one group
// ahead. G column (u=64) LDS-resident from a prologue fill.
// P-SUM TRICK (new): shup1 is linear, so the 4 per-duration shifts collapse
// to ONE: m = shup1((ly0+ly1)+(ly2+ly3)); the inner sum is shared with the
// c-column update. Bitwise-identical math, ~25% fewer chain instructions.
// INSTRUMENTATION: whole DP repeated REPS times (state reset each rep; only
// the last rep contributes to out) so k_dp's dispatch outlasts the harness
// fills and surfaces in the rocprof top-5 with full counters.
__global__ __launch_bounds__(256, 1) void k_dp(
    const float* __restrict__ ws, float* __restrict__ out)
{
  const int b  = blockIdx.x;
  const int wv = threadIdx.x >> 6;
  const int l  = threadIdx.x & 63;
  const float4* WB4p = (const float4*)ws + (size_t)b * (TP * TDT_U1);
  const float4* WY4p = (const float4*)(ws + OFF_PYD) + (size_t)b * (TP * TDT_U);
  const float4* GC4p = (const float4*)(ws + OFF_GC) + (size_t)b * TP;

  extern __shared__ float4 smem[];          // 45*128 ring + 275 G = 96.6 KB
  float4* ring = smem;
  float4* glds = smem + 45 * 128;

  for (int rep = 0; rep < REPS; ++rep) {
    // guard: prior rep's chain reads of ring thirds 1,2 must finish before
    // this rep's prologue overwrites them (no-op on rep 0)
    __syncthreads();

    // prologue: G column (lane-variant vector loads) + groups 0,1
    if (wv != 0) {
      for (int i = (threadIdx.x - 64); i < TP; i += 192) glds[i] = GC4p[i];
      fill_group(WB4p, WY4p, ring, 0, wv, l);
      fill_group(WB4p, WY4p, ring, 1, wv, l);
    }
    __syncthreads();

    // depth-5 FIFO: slot(s) = s%5 holds slice s
    float4 B0,B1,B2,B3,B4, Y0,Y1,Y2,Y3,Y4, G0,G1,G2,G3,G4;
    float a1 = 0.f, a2 = 0.f, a3 = 0.f, a4 = 0.f;
    float c1 = 0.f, c2 = 0.f, c3 = 0.f, c4 = 0.f;
    float L = 0.f;

#define LOADSLOT(S, RS, TPI) do {            \
    const int _r = (RS) * 128;               \
    B##S = ring[_r + l];                     \
    Y##S = ring[_r + 64 + l];                \
    G##S = glds[TPI];                        \
  } while (0)

    if (wv == 0) {
      // preload slices 1..5 (ring slots 0..4) into FIFO slots 1,2,3,4,0
      LOADSLOT(1, 0, 1); LOADSLOT(2, 1, 2); LOADSLOT(3, 2, 3);
      LOADSLOT(4, 3, 4); LOADSLOT(0, 4, 5);
      a1 = (l == 0) ? 1.f : 0.f;             // A = exp(alpha + SHIFT*t - L)
    }

  // step t: FIFO slots (t+3)%5..t%5 supply slices t+3..t; then load slice
  // t+5 from ring slot (t+4)%45 into FIFO slot t%5 (=S3).
#define STEP(S0,S1,S2,S3, RSL, TPI) do {                                     \
    float ly0 = a1 * Y##S0.x, ly1 = a2 * Y##S1.y,                            \
          ly2 = a3 * Y##S2.z, ly3 = a4 * Y##S3.w;                            \
    float P  = (ly0 + ly1) + (ly2 + ly3);                                    \
    float m  = shup1(P);                                                     \
    float anew = ((a1*B##S0.x + a2*B##S1.y) + (a3*B##S2.z + a4*B##S3.w)) + m;\
    float cnew = ((c1*G##S0.x + c2*G##S1.y) + (c3*G##S2.z + c4*G##S3.w)) + P;\
    a4 = a3; a3 = a2; a2 = a1; a1 = anew;                                    \
    c4 = c3; c3 = c2; c2 = c1; c1 = cnew;                                    \
    LOADSLOT(S3, RSL, TPI);                                                  \
  } while (0)

    for (int i = 0, tb = 1; i < 17; ++i, tb += 15) {
      __syncthreads();
      if (wv != 0) {
        if (i < 16) fill_group(WB4p, WY4p, ring, i + 2, wv, l);
      } else {
        const int rbA = 15 * (i % 3);        // third holding group i
        const int rbB = 15 * ((i + 1) % 3);  // third holding group i+1
        if (i) {
          // uniform renorm: 1/max(two band probes); bookkeeping in L
          const float r1 = __shfl(a1, tb >> 3);
          const float r2 = __shfl(a1, tb >> 2);
          const float rl = fmaxf(r1, r2);
          const float sc = (rl > 1e-30f) ? (1.0f / rl) : 1.0f;
          L -= __logf(sc);
          a1 *= sc; a2 *= sc; a3 *= sc; a4 *= sc;
          c1 *= sc; c2 *= sc; c3 *= sc; c4 *= sc;
        }
        // tb%5 == 1 always, so the slot pattern repeats every 5 steps
        STEP(4,3,2,1, rbA + 5,  tb + 5);
        STEP(0,4,3,2, rbA + 6,  tb + 6);
        STEP(1,0,4,3, rbA + 7,  tb + 7);
        STEP(2,1,0,4, rbA + 8,  tb + 8);
        STEP(3,2,1,0, rbA + 9,  tb + 9);
        STEP(4,3,2,1, rbA + 10, tb + 10);
        STEP(0,4,3,2, rbA + 11, tb + 11);
        STEP(1,0,4,3, rbA + 12, tb + 12);
        STEP(2,1,0,4, rbA + 13, tb + 13);
        STEP(3,2,1,0, rbA + 14, tb + 14);
        STEP(4,3,2,1, rbB + 0,  tb + 15);
        STEP(0,4,3,2, rbB + 1,  tb + 16);
        STEP(1,0,4,3, rbB + 2,  tb + 17);
        STEP(2,1,0,4, rbB + 3,  tb + 18);
        STEP(3,2,1,0, rbB + 4,  tb + 19);
      }
    }

    if (wv == 0 && l == 63 && rep == REPS - 1) {
      // ll = L - SHIFT*256 + log( sum_d C[256-d] * WG_d ); G from LDS
      const float sum = c1 * glds[259].x
                      + c2 * glds[258].y
                      + c3 * glds[257].z
                      + c4 * glds[256].w;
      const float ll = L - SHIFT * 256.0f + __logf(sum);
      atomicAdd(out, ll * (-1.0f / TDT_B));
    }
#undef STEP
#undef LOADSLOT
  }
}

extern "C" void kernel_launch(void* const* d_in, const int* in_sizes, int n_in,
                              void* d_out, int out_size, void* d_ws, size_t ws_size,
                              hipStream_t stream)
{
  const float* la = (const float*)d_in[0];   // label_acts    (B,T,U+1,V+1) f32
  const float* da = (const float*)d_in[1];   // duration_acts (B,T,U+1,D)   f32
  const int*   tg = (const int*)d_in[2];     // targets       (B,U)         i32
  float* ws  = (float*)d_ws;
  float* out = (float*)d_out;

  const int rows = TDT_B * TDT_T * TDT_U1;   // 133120
  k_prep<<<rows / 4, 256, 0, stream>>>(la, da, tg, ws, out);
  k_dp  <<<TDT_B, 256, (45 * 128 + TP) * sizeof(float4), stream>>>(ws, out);
}

// Round 14
// 78.628 us; speedup vs baseline: 3.4989x; 3.4989x over previous
//
#include <hip/hip_runtime.h>

// TDT loss, fixed shapes from setup_inputs():
#define TDT_B  8
#define TDT_T  256
#define TDT_U  64
#define TDT_U1 65
#define TDT_V1 513   // V+1, blank index = 512
#define TP     275   // 4 zero-pad slices + 256 + slack
#define SIG    0.05f
#define SHIFT  3.0f  // exponent shift PER TIME-STEP: duration-d weight carries SHIFT*d

// ws layout (floats):
//   WB: float4[B][TP][U1] = exp(lpb + ld_i - SIG + SHIFT*(i+1))
//   WY: float4[B][TP][U]  = exp(lpy + ld_i - SIG + SHIFT*(i+1))
//   GC: float4[B][TP]     = WB[b][tp][u=64]  (compact G column)
#define OFF_PYD 572000                        // 8*275*65*4
#define OFF_GC  1135200                       // + 8*275*64*4; GC = 8800 floats

// Kernel 1: per-(b,t,u) row log-softmax over 513 labels (wave per row, float2
// loads with odd-row alignment shim), duration log-softmax over 4, write
// EXP-DOMAIN W records with per-duration scale e^{SHIFT*d}. Zero pads tau<0.
__global__ __launch_bounds__(256) void k_prep(
    const float* __restrict__ la, const float* __restrict__ da,
    const int* __restrict__ tgt, float* __restrict__ ws,
    float* __restrict__ out)
{
  if (blockIdx.x == 0 && threadIdx.x == 0) out[0] = 0.f;

  const int l = threadIdx.x & 63;
  const int r = (blockIdx.x << 2) + (threadIdx.x >> 6);   // row in [0, B*T*U1)
  const int u  = r % TDT_U1;
  const int bt = r / TDT_U1;
  const int t  = bt & (TDT_T - 1);
  const int b  = bt >> 8;

  const float* row = la + (size_t)r * TDT_V1;
  const int ofs = r & 1;                    // odd rows: shift by 1 for 8B align
  const float2* p2 = (const float2*)(row + ofs);
  float2 w[4];
#pragma unroll
  for (int k = 0; k < 4; ++k) w[k] = p2[l + (k << 6)];  // elems ofs+2l+128k+{0,1}
  const float extra = row[ofs ? 0 : 512];   // the one element outside the vec span

  float m = extra;
#pragma unroll
  for (int k = 0; k < 4; ++k) m = fmaxf(m, fmaxf(w[k].x, w[k].y));
#pragma unroll
  for (int off = 32; off; off >>= 1) m = fmaxf(m, __shfl_xor(m, off));
  float s = (l == 0) ? __expf(extra - m) : 0.f;
#pragma unroll
  for (int k = 0; k < 4; ++k) s += __expf(w[k].x - m) + __expf(w[k].y - m);
#pragma unroll
  for (int off = 32; off; off >>= 1) s += __shfl_xor(s, off);
  const float lse = m + __logf(s);

  // duration log-softmax (uniform per wave)
  const float4 dv = *(const float4*)(da + ((size_t)r << 2));
  const float m4 = fmaxf(fmaxf(dv.x, dv.y), fmaxf(dv.z, dv.w));
  const float l4 = m4 + __logf(__expf(dv.x - m4) + __expf(dv.y - m4) +
                               __expf(dv.z - m4) + __expf(dv.w - m4));
  // per-duration: ld_i - l4 + SHIFT*(i+1)  (scale-consistent exp domain)
  const float d0 = dv.x - l4 + SHIFT * 1.0f;
  const float d1 = dv.y - l4 + SHIFT * 2.0f;
  const float d2 = dv.z - l4 + SHIFT * 3.0f;
  const float d3 = dv.w - l4 + SHIFT * 4.0f;

  float4* WB4 = (float4*)ws;
  float4* WY4 = (float4*)(ws + OFF_PYD);
  float4* GC4 = (float4*)(ws + OFF_GC);

  const int tp = t + 4;
  // blank logit = elem 512: ofs==0 -> extra (owner lane 0); ofs==1 -> w[3].y (lane 63)
  const float xb = ofs ? w[3].y : extra;
  if (l == (ofs ? 63 : 0)) {
    const float pb = xb - lse - SIG;
    const float4 wb = make_float4(__expf(pb + d0), __expf(pb + d1),
                                  __expf(pb + d2), __expf(pb + d3));
    WB4[(b * TP + tp) * TDT_U1 + u] = wb;
    if (u == TDT_U) GC4[b * TP + tp] = wb;
  }

  // target gather (exactly one lane owns it); static indices only
  const int tg = (u < TDT_U) ? tgt[b * TDT_U + u] : -1;   // tg in [0,512)
  bool own = false; float vt = 0.f;
#pragma unroll
  for (int k = 0; k < 4; ++k) {
    const int base = ofs + ((l + (k << 6)) << 1);
    if (base == tg)     { vt = w[k].x; own = true; }
    if (base + 1 == tg) { vt = w[k].y; own = true; }
  }
  if (ofs && tg == 0 && l == 0) { vt = extra; own = true; }
  if (own) {
    const float py = vt - lse - SIG;
    WY4[(b * TP + tp) * TDT_U + u] =
        make_float4(__expf(py + d0), __expf(py + d1), __expf(py + d2), __expf(py + d3));
  }

  // zero pads for tau < 0 (slices tp = 0..3): exp(-inf) = 0
  if (t < 4 && l == 0) {
    const float4 z4 = make_float4(0.f, 0.f, 0.f, 0.f);
    WB4[(b * TP + t) * TDT_U1 + u] = z4;
    if (u == TDT_U) GC4[b * TP + t] = z4;
    if (u < TDT_U)  WY4[(b * TP + t) * TDT_U + u] = z4;
  }
}

// DPP wave_shr:1 (ctrl 0x138), bound_ctrl=1 -> lane 0 reads 0. VALU-pipe
// lane shift replacing ds_bpermute on the serial t-chain.
__device__ __forceinline__ float shup1(float x) {
  const int r = __builtin_amdgcn_update_dpp(
      0, __float_as_int(x), 0x138, 0xf, 0xf, true);
  return __int_as_float(r);
}

// Direct HBM->LDS DMA, 16B/lane: lane l's data lands at ldsbase + l*16.
__device__ __forceinline__ void gl2lds16(const float4* g, float4* lds) {
  __builtin_amdgcn_global_load_lds(
      (const __attribute__((address_space(1))) void*)g,
      (__attribute__((address_space(3))) void*)lds, 16, 0, 0);
}

// Loader helper: fill group j (slices 15j+1 .. 15j+15) into ring third j%3.
// Slice s -> ring slot (s-1)%45; slot holds B[u=0..63] then Y[u=0..63].
__device__ __forceinline__ void fill_group(
    const float4* __restrict__ WB4p, const float4* __restrict__ WY4p,
    float4* ring, int j, int wv, int l)
{
  const int sb = 15 * j + wv;               // this wave's first slice in group
  const int rb = 15 * (j % 3) + (wv - 1);   // its first ring slot
#pragma unroll
  for (int k = 0; k < 5; ++k) {
    const int s    = sb + 3 * k;
    const int slot = rb + 3 * k;
    gl2lds16(WB4p + (size_t)s * TDT_U1 + l, ring + slot * 128);
    gl2lds16(WY4p + (size_t)s * TDT_U  + l, ring + slot * 128 + 64);
  }
}

// Kernel 2: forward DP, exp domain. 8 blocks (one per b) x 4 waves.
// Wave 0: serial chain with a DEPTH-15 named register FIFO (lead-12: the
// ds_read for slice t+15 issues at step t, first use at step t+12 -> ~500+
// cycles of slack, vs the depth-5 FIFO's lead-2 that left ~140 cyc/step of
// exposed LDS latency -- R13's counters: VALUBusy 19% of chain time).
// Waves 1-3: global_load_lds-stream W slices one group ahead into the
// 45-slice LDS ring. G column LDS-resident from a prologue fill.
// ~270 VGPR; __launch_bounds__(256,1) -> 1 wave/SIMD -> 512 VGPR budget, no spill.
__global__ __launch_bounds__(256, 1) void k_dp(
    const float* __restrict__ ws, float* __restrict__ out)
{
  const int b  = blockIdx.x;
  const int wv = threadIdx.x >> 6;
  const int l  = threadIdx.x & 63;
  const float4* WB4p = (const float4*)ws + (size_t)b * (TP * TDT_U1);
  const float4* WY4p = (const float4*)(ws + OFF_PYD) + (size_t)b * (TP * TDT_U);
  const float4* GC4p = (const float4*)(ws + OFF_GC) + (size_t)b * TP;

  extern __shared__ float4 smem[];          // 45*128 ring + 275 G = 96.6 KB
  float4* ring = smem;
  float4* glds = smem + 45 * 128;

  // prologue: G column (lane-variant vector loads) + groups 0,1
  if (wv != 0) {
    for (int i = (threadIdx.x - 64); i < TP; i += 192) glds[i] = GC4p[i];
    fill_group(WB4p, WY4p, ring, 0, wv, l);
    fill_group(WB4p, WY4p, ring, 1, wv, l);
  }
  __syncthreads();

  // depth-15 FIFO: slot(s) = s%15 holds slice s
  float4 B0,B1,B2,B3,B4,B5,B6,B7,B8,B9,B10,B11,B12,B13,B14;
  float4 Y0,Y1,Y2,Y3,Y4,Y5,Y6,Y7,Y8,Y9,Y10,Y11,Y12,Y13,Y14;
  float4 G0,G1,G2,G3,G4,G5,G6,G7,G8,G9,G10,G11,G12,G13,G14;
  float a1 = 0.f, a2 = 0.f, a3 = 0.f, a4 = 0.f;
  float c1 = 0.f, c2 = 0.f, c3 = 0.f, c4 = 0.f;
  float L = 0.f;

#define LOADSLOT(S, RS, TPI) do {            \
    const int _r = (RS) * 128;               \
    B##S = ring[_r + l];                     \
    Y##S = ring[_r + 64 + l];                \
    G##S = glds[TPI];                        \
  } while (0)

  if (wv == 0) {
    // preload slices 1..15 (ring slots 0..14, third 0) into FIFO slot s%15
    LOADSLOT(1, 0, 1);   LOADSLOT(2, 1, 2);   LOADSLOT(3, 2, 3);
    LOADSLOT(4, 3, 4);   LOADSLOT(5, 4, 5);   LOADSLOT(6, 5, 6);
    LOADSLOT(7, 6, 7);   LOADSLOT(8, 7, 8);   LOADSLOT(9, 8, 9);
    LOADSLOT(10, 9, 10); LOADSLOT(11, 10, 11);LOADSLOT(12, 11, 12);
    LOADSLOT(13, 12, 13);LOADSLOT(14, 13, 14);LOADSLOT(0, 14, 15);
    a1 = (l == 0) ? 1.f : 0.f;               // A = exp(alpha + SHIFT*t - L)
  }

  // step t: FIFO slots (t+3)%15..t%15 supply slices t+3..t; then load slice
  // t+15 from ring slot (t+14)%45 into FIFO slot t%15 (=S3). Lead-12.
  // P-sum: shup1 is linear -> one DPP on the shared ly-sum P.
#define STEP(S0,S1,S2,S3, RSL, TPI) do {                                     \
    float ly0 = a1 * Y##S0.x, ly1 = a2 * Y##S1.y,                            \
          ly2 = a3 * Y##S2.z, ly3 = a4 * Y##S3.w;                            \
    float P  = (ly0 + ly1) + (ly2 + ly3);                                    \
    float m  = shup1(P);                                                     \
    float anew = ((a1*B##S0.x + a2*B##S1.y) + (a3*B##S2.z + a4*B##S3.w)) + m;\
    float cnew = ((c1*G##S0.x + c2*G##S1.y) + (c3*G##S2.z + c4*G##S3.w)) + P;\
    a4 = a3; a3 = a2; a2 = a1; a1 = anew;                                    \
    c4 = c3; c3 = c2; c2 = c1; c1 = cnew;                                    \
    LOADSLOT(S3, RSL, TPI);                                                  \
  } while (0)

  for (int i = 0, tb = 1; i < 17; ++i, tb += 15) {
    __syncthreads();
    if (wv != 0) {
      if (i < 16) fill_group(WB4p, WY4p, ring, i + 2, wv, l);
    } else {
      const int rbB = 15 * ((i + 1) % 3);    // third holding group i+1
      if (i) {
        // uniform renorm: 1/max(two band probes); bookkeeping in L
        const float r1 = __shfl(a1, tb >> 3);
        const float r2 = __shfl(a1, tb >> 2);
        const float rl = fmaxf(r1, r2);
        const float sc = (rl > 1e-30f) ? (1.0f / rl) : 1.0f;
        L -= __logf(sc);
        a1 *= sc; a2 *= sc; a3 *= sc; a4 *= sc;
        c1 *= sc; c2 *= sc; c3 *= sc; c4 *= sc;
      }
      // tb%15 == 1 always; loads pull slices tb+15..tb+29 (group i+1) from
      // ring slots rbB+0..14 (filled during iteration i-1)
      STEP(4,3,2,1,     rbB + 0,  tb + 15);
      STEP(5,4,3,2,     rbB + 1,  tb + 16);
      STEP(6,5,4,3,     rbB + 2,  tb + 17);
      STEP(7,6,5,4,     rbB + 3,  tb + 18);
      STEP(8,7,6,5,     rbB + 4,  tb + 19);
      STEP(9,8,7,6,     rbB + 5,  tb + 20);
      STEP(10,9,8,7,    rbB + 6,  tb + 21);
      STEP(11,10,9,8,   rbB + 7,  tb + 22);
      STEP(12,11,10,9,  rbB + 8,  tb + 23);
      STEP(13,12,11,10, rbB + 9,  tb + 24);
      STEP(14,13,12,11, rbB + 10, tb + 25);
      STEP(0,14,13,12,  rbB + 11, tb + 26);
      STEP(1,0,14,13,   rbB + 12, tb + 27);
      STEP(2,1,0,14,    rbB + 13, tb + 28);
      STEP(3,2,1,0,     rbB + 14, tb + 29);
    }
  }

  if (wv == 0 && l == 63) {
    // ll = L - SHIFT*256 + log( sum_d C[256-d] * WG_d ); G from LDS glds[tp]
    const float sum = c1 * glds[259].x
                    + c2 * glds[258].y
                    + c3 * glds[257].z
                    + c4 * glds[256].w;
    const float ll = L - SHIFT * 256.0f + __logf(sum);
    atomicAdd(out, ll * (-1.0f / TDT_B));
  }
#undef STEP
#undef LOADSLOT
}

extern "C" void kernel_launch(void* const* d_in, const int* in_sizes, int n_in,
                              void* d_out, int out_size, void* d_ws, size_t ws_size,
                              hipStream_t stream)
{
  const float* la = (const float*)d_in[0];   // label_acts    (B,T,U+1,V+1) f32
  const float* da = (const float*)d_in[1];   // duration_acts (B,T,U+1,D)   f32
  const int*   tg = (const int*)d_in[2];     // targets       (B,U)         i32
  float* ws  = (float*)d_ws;
  float* out = (float*)d_out;

  const int rows = TDT_B * TDT_T * TDT_U1;   // 133120
  k_prep<<<rows / 4, 256, 0, stream>>>(la, da, tg, ws, out);
  k_dp  <<<TDT_B, 256, (45 * 128 + TP) * sizeof(float4), stream>>>(ws, out);
}